// Round 2
// baseline (23335.509 us; speedup 1.0000x reference)
//
#include <hip/hip_runtime.h>
#include <cmath>

typedef unsigned short u16;
typedef unsigned int u32;
typedef __attribute__((ext_vector_type(8))) short s16x8;
typedef __attribute__((ext_vector_type(8))) unsigned short u16x8;
typedef __attribute__((ext_vector_type(4))) unsigned short u16x4;
typedef __attribute__((ext_vector_type(4))) float f32x4;

#define LN_EPS 1e-6f

// ---------- helpers ----------
__device__ __forceinline__ u16 f2bf(float f) {
  union { float f; u32 u; } v; v.f = f;
  u32 r = v.u + 0x7FFFu + ((v.u >> 16) & 1u);
  return (u16)(r >> 16);
}
__device__ __forceinline__ float bf2f(u16 h) {
  union { u32 u; float f; } v; v.u = ((u32)h) << 16; return v.f;
}

__device__ __forceinline__ void gload_lds16(const void* g, void* l) {
  __builtin_amdgcn_global_load_lds(
      (__attribute__((address_space(1))) void*)g,
      (__attribute__((address_space(3))) void*)l, 16, 0, 0);
}

__device__ __forceinline__ f32x4 mfma16(s16x8 a, s16x8 b, f32x4 c) {
  return __builtin_amdgcn_mfma_f32_16x16x32_bf16(a, b, c, 0, 0, 0);
}

// all-wg barrier: each wg sets flags[wg]=target (release/agent), wave0 polls all 256
__device__ __forceinline__ void gbar(unsigned* flags, unsigned target) {
  __syncthreads();
  if (threadIdx.x == 0)
    __hip_atomic_store(&flags[blockIdx.x], target, __ATOMIC_RELEASE, __HIP_MEMORY_SCOPE_AGENT);
  if (threadIdx.x < 64) {
    int l = threadIdx.x;
    for (;;) {
      unsigned a0 = __hip_atomic_load(&flags[l],       __ATOMIC_ACQUIRE, __HIP_MEMORY_SCOPE_AGENT);
      unsigned a1 = __hip_atomic_load(&flags[l + 64],  __ATOMIC_ACQUIRE, __HIP_MEMORY_SCOPE_AGENT);
      unsigned a2 = __hip_atomic_load(&flags[l + 128], __ATOMIC_ACQUIRE, __HIP_MEMORY_SCOPE_AGENT);
      unsigned a3 = __hip_atomic_load(&flags[l + 192], __ATOMIC_ACQUIRE, __HIP_MEMORY_SCOPE_AGENT);
      bool ok = (a0 >= target) & (a1 >= target) & (a2 >= target) & (a3 >= target);
      if (__all(ok)) break;
    }
  }
  __syncthreads();
}

// ---------- kernel 1: Xc[m][2048] = bf16(concat(inputo, attn)) for chunk rows m=b*Tc+tc ----------
__global__ __launch_bounds__(256) void cvtx_kernel(const float* __restrict__ inputo,
                                                   const float* __restrict__ attn,
                                                   u16* __restrict__ Xc,
                                                   int t0, int log2Tc) {
  size_t i = ((size_t)blockIdx.x * 256 + threadIdx.x) * 4; // over M*1024, grid exact
  size_t m = i >> 10, d = i & 1023;
  int tc = (int)(m & ((1u << log2Tc) - 1));
  int b  = (int)(m >> log2Tc);
  size_t src = ((size_t)b * 256 + t0 + tc) * 1024 + d;
  float4 a = *(const float4*)(inputo + src);
  float4 v = *(const float4*)(attn + src);
  u16x4 va = { f2bf(a.x), f2bf(a.y), f2bf(a.z), f2bf(a.w) };
  u16x4 vb = { f2bf(v.x), f2bf(v.y), f2bf(v.z), f2bf(v.w) };
  *(u16x4*)(Xc + m * 2048 + d) = va;
  *(u16x4*)(Xc + m * 2048 + 1024 + d) = vb;
}

// ---------- kernel 2: WT[n][k] = bf16(W[k][n])  (W [3072][4096] -> WT [4096][3072]) ----------
__global__ __launch_bounds__(256) void wtrans_kernel(const float* __restrict__ W,
                                                     u16* __restrict__ WT) {
  __shared__ float tile[32][33];
  int bn = blockIdx.x & 127;
  int bk = blockIdx.x >> 7;
  int n0 = bn * 32, k0 = bk * 32;
  int tx = threadIdx.x & 31, ty = threadIdx.x >> 5;
#pragma unroll
  for (int i = 0; i < 32; i += 8)
    tile[ty + i][tx] = W[(size_t)(k0 + ty + i) * 4096 + n0 + tx];
  __syncthreads();
#pragma unroll
  for (int i = 0; i < 32; i += 8)
    WT[(size_t)(n0 + ty + i) * 3072 + k0 + tx] = f2bf(tile[tx][ty + i]);
}

// ---------- kernel 3: init hx, cx, flags ----------
__global__ __launch_bounds__(256) void init_kernel(const float* __restrict__ init_hx,
                                                   const float* __restrict__ init_cx,
                                                   u16* __restrict__ hx,
                                                   float* __restrict__ cxbuf,
                                                   unsigned* __restrict__ flags) {
  int i = blockIdx.x * 256 + threadIdx.x;
  if (i < 64 * 1024) {
    hx[i] = f2bf(init_hx[i & 1023]);
    cxbuf[i] = init_cx[i & 1023];
  }
  if (i < 256) flags[i] = 0;
}

// ---------- kernel 4: Zxc[m][n] = bf16( sum_k Xc[m][k]*WT[n][k] )   (m97-style 128x128 tile) ----------
__global__ __launch_bounds__(256) void gemm_zx_kernel(const u16* __restrict__ Xc,
                                                      const u16* __restrict__ WT,
                                                      u16* __restrict__ Zxc,
                                                      int log2nmt) {
  __shared__ u16 As[128 * 64];
  __shared__ u16 Bs[128 * 64];
  const int tid = threadIdx.x, lane = tid & 63, wave = tid >> 6;
  const int nmt_mask = (1 << log2nmt) - 1;
  int mt = blockIdx.x & nmt_mask;        // fast-varying: adjacent blocks share B panel
  int nt = blockIdx.x >> log2nmt;        // 0..31
  const size_t m0 = (size_t)mt * 128, n0 = (size_t)nt * 128;
  const int wm = (wave >> 1) * 64, wn = (wave & 1) * 64;
  const int l15 = lane & 15, kg = lane >> 4;
  const int s_r = lane >> 3;
  const int s_c = (lane & 7) * 8;

  f32x4 acc[4][4];
#pragma unroll
  for (int a = 0; a < 4; ++a)
#pragma unroll
    for (int b = 0; b < 4; ++b) acc[a][b] = (f32x4){0.f, 0.f, 0.f, 0.f};

  for (int k0 = 0; k0 < 2048; k0 += 64) {
#pragma unroll
    for (int it = 0; it < 4; ++it) {
      int ch = (wave << 2) + it;
      int row = (ch << 3) + s_r;
      gload_lds16(Xc + (m0 + row) * 2048 + k0 + s_c, (char*)As + (ch << 10));
      gload_lds16(WT + (n0 + row) * 3072 + k0 + s_c, (char*)Bs + (ch << 10));
    }
    __syncthreads();
#pragma unroll
    for (int kk = 0; kk < 2; ++kk) {
      s16x8 af[4], bf[4];
#pragma unroll
      for (int i = 0; i < 4; ++i)
        af[i] = *(const s16x8*)(As + (wm + i * 16 + l15) * 64 + kk * 32 + kg * 8);
#pragma unroll
      for (int i = 0; i < 4; ++i)
        bf[i] = *(const s16x8*)(Bs + (wn + i * 16 + l15) * 64 + kk * 32 + kg * 8);
#pragma unroll
      for (int mi = 0; mi < 4; ++mi)
#pragma unroll
        for (int ni = 0; ni < 4; ++ni)
          acc[mi][ni] = mfma16(af[mi], bf[ni], acc[mi][ni]);
    }
    __syncthreads();
  }
#pragma unroll
  for (int ni = 0; ni < 4; ++ni) {
    size_t n = n0 + wn + ni * 16 + l15;
#pragma unroll
    for (int mi = 0; mi < 4; ++mi) {
#pragma unroll
      for (int j = 0; j < 4; ++j) {
        size_t m = m0 + wm + mi * 16 + (kg << 2) + j;
        Zxc[m * 4096 + n] = f2bf(acc[mi][ni][j]);
      }
    }
  }
}

// ---------- kernel 5: persistent recurrence for one time chunk, 256 wgs ----------
// wg (rg, slice): rows rg*32..+32, features d0=slice*8..+8 across all 4 gates (32 cols)
__global__ __launch_bounds__(256, 1) void recurrent_kernel(
    const u16* __restrict__ Zxc, const u16* __restrict__ WT,
    const float* __restrict__ inputo, const float* __restrict__ bias,
    const float* __restrict__ ln_w, const float* __restrict__ ln_b,
    float* __restrict__ out, u16* __restrict__ hx, float* __restrict__ cxbuf,
    float* __restrict__ gpart, unsigned* __restrict__ flags,
    int t0, int log2Tc) {
  __shared__ u16 WhL[32][1032];     // [local col][k] padded (2-way bank alias only)
  __shared__ u16 hxS[32 * 1024];    // per-step hx stage, XOR-swizzled k8 within row
  __shared__ float spart[32][2][2]; // [row][sum/sumsq][nt]
  __shared__ float stot[32][2];
  __shared__ float zbuf[32][33];

  const int Tc = 1 << log2Tc;
  const int tid = threadIdx.x, lane = tid & 63, wave = tid >> 6;
  const int bid = blockIdx.x;
  const int rg = bid >> 7, slice = bid & 127;
  const int d0 = slice << 3;
  const int mt = wave >> 1, nt = wave & 1;
  const int l15 = lane & 15, kg = lane >> 4;
  const int arow = (mt << 4) + l15;                       // local row for A frag
  const int bcol = (nt << 4) + l15;                       // local col 0..31
  const int ncol = ((bcol >> 3) << 10) + d0 + (bcol & 7); // global col in [0,4096)
  const float lnw = ln_w[ncol], lnb = ln_b[ncol];
  const float bz = bias[ncol];
  // phase-B role: thread -> (row, feature)
  const int prow = tid >> 3, pf = tid & 7;
  const int prg = (rg << 5) + prow;
  const int pd = d0 + pf;
  float cx = cxbuf[prg * 1024 + pd];
  const float* inp_p = inputo + (size_t)prg * 262144 + pd;
  float* out_p = out + (size_t)prg * 262144 + pd;
  u16* hx_p = hx + prg * 1024 + pd;

  // preload Wh slice into LDS (lives for whole kernel): WhL[c][k] = W[2048+k][gate*1024+d0+f]
  for (int idx = tid; idx < 32 * 128; idx += 256) {
    int c = idx >> 7, ck = (idx & 127) << 3;
    int n = ((c >> 3) << 10) + d0 + (c & 7);
    *(u16x8*)(&WhL[c][ck]) = *(const u16x8*)(WT + (size_t)n * 3072 + 2048 + ck);
  }

  const int b0 = (rg << 5) + (mt << 4) + (kg << 2);
  const size_t zx_base = ((size_t)b0 << log2Tc) * 4096 + ncol;
  unsigned tgt = 2u * (unsigned)t0;

  for (int tc = 0; tc < Tc; ++tc) {
    const int t = t0 + tc;
    // ---- stage hx -> hxS (64KB) via global_load_lds; source pre-swizzled so
    // ds_read_b128 A-frags (stride 2048B) are conflict-free: slot k8' holds k8 = k8'^(row&7)
#pragma unroll
    for (int ii = 0; ii < 16; ++ii) {
      int i = (wave << 4) + ii;
      int row = i >> 1;
      int k8p = ((i & 1) << 6) | lane;
      const u16* src = hx + (((rg << 5) + row) << 10) + ((k8p ^ (row & 7)) << 3);
      gload_lds16(src, (char*)hxS + (i << 10));
    }
    // prefetch Zx (this lane's 4 accumulator slots, bias folded) and inputo (phase-B role)
    float zx[4];
#pragma unroll
    for (int j = 0; j < 4; ++j)
      zx[j] = bf2f(Zxc[zx_base + ((size_t)(j << log2Tc) + tc) * 4096]) + bz;
    const float inv = inp_p[(size_t)t << 10];
    __syncthreads(); // drains global_load_lds (vmcnt(0)) + makes WhL/hxS visible

    // ---- GEMM: z[32 rows][32 cols] slice; wave = one 16x16 tile, K=1024
    f32x4 acc = (f32x4){0.f, 0.f, 0.f, 0.f};
#pragma unroll 8
    for (int kk = 0; kk < 32; ++kk) {
      int k8 = (kk << 2) | kg;
      s16x8 a = *(const s16x8*)(hxS + (arow << 10) + ((k8 ^ (arow & 7)) << 3));
      s16x8 b = *(const s16x8*)(&WhL[bcol][k8 << 3]);
      acc = mfma16(a, b, acc);
    }

    // ---- z, per-row partial sums over this wg's 32 cols
    float z[4], s1[4], s2[4];
#pragma unroll
    for (int j = 0; j < 4; ++j) { z[j] = acc[j] + zx[j]; s1[j] = z[j]; s2[j] = z[j] * z[j]; }
#pragma unroll
    for (int off = 1; off < 16; off <<= 1) {
#pragma unroll
      for (int j = 0; j < 4; ++j) {
        s1[j] += __shfl_xor(s1[j], off, 64);
        s2[j] += __shfl_xor(s2[j], off, 64);
      }
    }
    if (l15 == 0) {
#pragma unroll
      for (int j = 0; j < 4; ++j) {
        spart[(mt << 4) + (kg << 2) + j][0][nt] = s1[j];
        spart[(mt << 4) + (kg << 2) + j][1][nt] = s2[j];
      }
    }
    __syncthreads();
    if (tid < 64) {
      int row = tid >> 1, kind = tid & 1;
      float tot = spart[row][kind][0] + spart[row][kind][1];
      gpart[(size_t)((((rg << 5) + row) << 1) + kind) * 128 + slice] = tot;
    }
    __threadfence();
    gbar(flags, ++tgt); // stats partials visible everywhere

    // ---- phase B: reduce stats, LN, gates, state update
    if (tid < 64) {
      int row = tid >> 1, kind = tid & 1;
      const float4* p = (const float4*)(gpart + (size_t)((((rg << 5) + row) << 1) + kind) * 128);
      float s = 0.f;
#pragma unroll 4
      for (int q = 0; q < 32; ++q) { float4 v = p[q]; s += (v.x + v.y) + (v.z + v.w); }
      stot[row][kind] = s;
    }
    __syncthreads();
#pragma unroll
    for (int j = 0; j < 4; ++j) {
      int row = (mt << 4) + (kg << 2) + j;
      float mean = stot[row][0] * (1.f / 4096.f);
      float var = stot[row][1] * (1.f / 4096.f) - mean * mean;
      float rstd = 1.f / sqrtf(var + LN_EPS);
      zbuf[row][bcol] = (z[j] - mean) * rstd * lnw + lnb;
    }
    __syncthreads();
    {
      float z0 = zbuf[prow][pf], z1 = zbuf[prow][8 + pf];
      float z2 = zbuf[prow][16 + pf], z3 = zbuf[prow][24 + pf];
      float ig = 1.f / (1.f + expf(-z0));
      float fg = 1.f / (1.f + expf(-z1));
      float og = 1.f / (1.f + expf(-z2));
      float hid = 0.5f * z3 * (1.f + erff(z3 * 0.70710678118654752f));
      cx = fg * cx + ig * hid;
      float hxv = og * cx;
      out_p[(size_t)t << 10] = hxv + inv;
      hx_p[0] = f2bf(hxv);
    }
    __threadfence();
    gbar(flags, ++tgt); // hx(t) visible before anyone stages step t+1
  }
  cxbuf[prg * 1024 + pd] = cx;
}

// ---------- launch ----------
extern "C" void kernel_launch(void* const* d_in, const int* in_sizes, int n_in,
                              void* d_out, int out_size, void* d_ws, size_t ws_size,
                              hipStream_t stream) {
  const float* inputo  = (const float*)d_in[0];
  const float* attn    = (const float*)d_in[1];
  const float* W       = (const float*)d_in[2];
  const float* bias    = (const float*)d_in[3];
  const float* ln_w    = (const float*)d_in[4];
  const float* ln_b    = (const float*)d_in[5];
  const float* init_hx = (const float*)d_in[6];
  const float* init_cx = (const float*)d_in[7];
  float* out = (float*)d_out;

  // choose time-chunk Tc (power of 2) so workspace fits; best-effort at Tc=4
  const size_t WT_BYTES = (size_t)4096 * 3072 * 2;       // 24 MiB
  const size_t TAIL     = 131072 + 262144 + 65536 + 1024; // hx, cx, gpart, flags
  int log2Tc = 7;
  for (; log2Tc > 2; --log2Tc) {
    size_t Tc = (size_t)1 << log2Tc;
    size_t need = WT_BYTES + Tc * 262144 /*Xc*/ + Tc * 524288 /*Zxc*/ + TAIL;
    if (need <= ws_size) break;
  }
  const int Tc = 1 << log2Tc;
  const int nchunks = 256 / Tc;

  char* ws = (char*)d_ws;
  size_t off = 0;
  u16* WT       = (u16*)(ws + off); off += WT_BYTES;
  u16* Xc       = (u16*)(ws + off); off += (size_t)Tc * 262144;
  u16* Zxc      = (u16*)(ws + off); off += (size_t)Tc * 524288;
  u16* hx       = (u16*)(ws + off); off += 131072;
  float* cxbuf  = (float*)(ws + off); off += 262144;
  float* gpart  = (float*)(ws + off); off += 65536;
  unsigned* flg = (unsigned*)(ws + off);

  wtrans_kernel<<<12288, 256, 0, stream>>>(W, WT);
  init_kernel<<<256, 256, 0, stream>>>(init_hx, init_cx, hx, cxbuf, flg);

  for (int c = 0; c < nchunks; ++c) {
    int t0 = c * Tc;
    cvtx_kernel<<<64 * Tc, 256, 0, stream>>>(inputo, attn, Xc, t0, log2Tc);
    gemm_zx_kernel<<<(Tc / 2) * 32, 256, 0, stream>>>(Xc, WT, Zxc, log2Tc - 1);
    recurrent_kernel<<<256, 256, 0, stream>>>(Zxc, WT, inputo, bias, ln_w, ln_b,
                                              out, hx, cxbuf, gpart, flg, t0, log2Tc);
  }
}

// Round 3
// 5747.772 us; speedup vs baseline: 4.0599x; 4.0599x over previous
//
#include <hip/hip_runtime.h>
#include <cmath>

typedef unsigned short u16;
typedef unsigned int u32;
typedef __attribute__((ext_vector_type(8))) short s16x8;
typedef __attribute__((ext_vector_type(8))) unsigned short u16x8;
typedef __attribute__((ext_vector_type(4))) unsigned short u16x4;
typedef __attribute__((ext_vector_type(4))) float f32x4;

#define LN_EPS 1e-6f

// ---------- helpers ----------
__device__ __forceinline__ u16 f2bf(float f) {
  union { float f; u32 u; } v; v.f = f;
  u32 r = v.u + 0x7FFFu + ((v.u >> 16) & 1u);
  return (u16)(r >> 16);
}
__device__ __forceinline__ float bf2f(u16 h) {
  union { u32 u; float f; } v; v.u = ((u32)h) << 16; return v.f;
}

__device__ __forceinline__ void gload_lds16(const void* g, void* l) {
  __builtin_amdgcn_global_load_lds(
      (__attribute__((address_space(1))) void*)g,
      (__attribute__((address_space(3))) void*)l, 16, 0, 0);
}

__device__ __forceinline__ f32x4 mfma16(s16x8 a, s16x8 b, f32x4 c) {
  return __builtin_amdgcn_mfma_f32_16x16x32_bf16(a, b, c, 0, 0, 0);
}

// machine barrier: 64 wgs arrive on 8 padded sub-counters (by wslice&7);
// relaxed poll by 8 lanes, single release fence before arrival, single
// acquire fence after exit. skip_poll on the chunk's last event.
__device__ __forceinline__ void mbar(unsigned* flags, unsigned* mycnt, int rg,
                                     unsigned tgt, bool skip_poll) {
  __syncthreads(); // all waves' stores drained (vmcnt0 before s_barrier)
  if (threadIdx.x == 0) {
    __builtin_amdgcn_fence(__ATOMIC_RELEASE, "agent");
    __hip_atomic_fetch_add(mycnt, 1u, __ATOMIC_RELAXED, __HIP_MEMORY_SCOPE_AGENT);
  }
  if (!skip_poll) {
    if (threadIdx.x < 64) {
      int l = threadIdx.x;
      unsigned v;
      do {
        v = (l < 8) ? __hip_atomic_load(flags + (((rg << 3) + l) << 5),
                                        __ATOMIC_RELAXED, __HIP_MEMORY_SCOPE_AGENT)
                    : tgt;
      } while (__all(v >= tgt) == 0);
    }
    __syncthreads();
    __builtin_amdgcn_fence(__ATOMIC_ACQUIRE, "agent");
  }
}

// ---------- kernel 1: Xc[m][2048] = bf16(concat(inputo, attn)), m=b*Tc+tc ----------
__global__ __launch_bounds__(256) void cvtx_kernel(const float* __restrict__ inputo,
                                                   const float* __restrict__ attn,
                                                   u16* __restrict__ Xc,
                                                   int t0, int log2Tc) {
  size_t i = ((size_t)blockIdx.x * 256 + threadIdx.x) * 4;
  size_t m = i >> 10, d = i & 1023;
  int tc = (int)(m & ((1u << log2Tc) - 1));
  int b  = (int)(m >> log2Tc);
  size_t src = ((size_t)b * 256 + t0 + tc) * 1024 + d;
  float4 a = *(const float4*)(inputo + src);
  float4 v = *(const float4*)(attn + src);
  u16x4 va = { f2bf(a.x), f2bf(a.y), f2bf(a.z), f2bf(a.w) };
  u16x4 vb = { f2bf(v.x), f2bf(v.y), f2bf(v.z), f2bf(v.w) };
  *(u16x4*)(Xc + m * 2048 + d) = va;
  *(u16x4*)(Xc + m * 2048 + 1024 + d) = vb;
}

// ---------- kernel 2: WT[n][k] = bf16(W[k][n]) ----------
__global__ __launch_bounds__(256) void wtrans_kernel(const float* __restrict__ W,
                                                     u16* __restrict__ WT) {
  __shared__ float tile[32][33];
  int bn = blockIdx.x & 127;
  int bk = blockIdx.x >> 7;
  int n0 = bn * 32, k0 = bk * 32;
  int tx = threadIdx.x & 31, ty = threadIdx.x >> 5;
#pragma unroll
  for (int i = 0; i < 32; i += 8)
    tile[ty + i][tx] = W[(size_t)(k0 + ty + i) * 4096 + n0 + tx];
  __syncthreads();
#pragma unroll
  for (int i = 0; i < 32; i += 8)
    WT[(size_t)(n0 + ty + i) * 3072 + k0 + tx] = f2bf(tile[tx][ty + i]);
}

// ---------- kernel 3: init hx, cx, flags ----------
__global__ __launch_bounds__(256) void init_kernel(const float* __restrict__ init_hx,
                                                   const float* __restrict__ init_cx,
                                                   u16* __restrict__ hx,
                                                   float* __restrict__ cxbuf,
                                                   unsigned* __restrict__ flags) {
  int i = blockIdx.x * 256 + threadIdx.x;
  if (i < 64 * 1024) {
    hx[i] = f2bf(init_hx[i & 1023]);
    cxbuf[i] = init_cx[i & 1023];
  }
  if (i < 512) flags[i] = 0;
}

// ---------- kernel 4: Zxc[m][n] = bf16( sum_k Xc[m][k]*WT[n][k] ) ----------
__global__ __launch_bounds__(256) void gemm_zx_kernel(const u16* __restrict__ Xc,
                                                      const u16* __restrict__ WT,
                                                      u16* __restrict__ Zxc,
                                                      int log2nmt) {
  __shared__ u16 As[128 * 64];
  __shared__ u16 Bs[128 * 64];
  const int tid = threadIdx.x, lane = tid & 63, wave = tid >> 6;
  const int nmt_mask = (1 << log2nmt) - 1;
  int mt = blockIdx.x & nmt_mask;
  int nt = blockIdx.x >> log2nmt;
  const size_t m0 = (size_t)mt * 128, n0 = (size_t)nt * 128;
  const int wm = (wave >> 1) * 64, wn = (wave & 1) * 64;
  const int l15 = lane & 15, kg = lane >> 4;
  const int s_r = lane >> 3;
  const int s_c = (lane & 7) * 8;

  f32x4 acc[4][4];
#pragma unroll
  for (int a = 0; a < 4; ++a)
#pragma unroll
    for (int b = 0; b < 4; ++b) acc[a][b] = (f32x4){0.f, 0.f, 0.f, 0.f};

  for (int k0 = 0; k0 < 2048; k0 += 64) {
#pragma unroll
    for (int it = 0; it < 4; ++it) {
      int ch = (wave << 2) + it;
      int row = (ch << 3) + s_r;
      gload_lds16(Xc + (m0 + row) * 2048 + k0 + s_c, (char*)As + (ch << 10));
      gload_lds16(WT + (n0 + row) * 3072 + k0 + s_c, (char*)Bs + (ch << 10));
    }
    __syncthreads();
#pragma unroll
    for (int kk = 0; kk < 2; ++kk) {
      s16x8 af[4], bf[4];
#pragma unroll
      for (int i = 0; i < 4; ++i)
        af[i] = *(const s16x8*)(As + (wm + i * 16 + l15) * 64 + kk * 32 + kg * 8);
#pragma unroll
      for (int i = 0; i < 4; ++i)
        bf[i] = *(const s16x8*)(Bs + (wn + i * 16 + l15) * 64 + kk * 32 + kg * 8);
#pragma unroll
      for (int mi = 0; mi < 4; ++mi)
#pragma unroll
        for (int ni = 0; ni < 4; ++ni)
          acc[mi][ni] = mfma16(af[mi], bf[ni], acc[mi][ni]);
    }
    __syncthreads();
  }
#pragma unroll
  for (int ni = 0; ni < 4; ++ni) {
    size_t n = n0 + wn + ni * 16 + l15;
#pragma unroll
    for (int mi = 0; mi < 4; ++mi) {
#pragma unroll
      for (int j = 0; j < 4; ++j) {
        size_t m = m0 + wm + mi * 16 + (kg << 2) + j;
        Zxc[m * 4096 + n] = f2bf(acc[mi][ni][j]);
      }
    }
  }
}

// ---------- kernel 5: persistent recurrence, 2 machines x 64 wgs x 256 thr ----------
// machine rg: rows rg*32..+32 (32 rows), all 4096 cols.
// wg wslice: features f0=wslice*16..+16, all 4 gates (64 cols). wave w = gate w.
// Wh B-fragments live in VGPRs (128/lane). hx staged to LDS per step.
__global__ __launch_bounds__(256, 1) void recurrent_kernel(
    const u16* __restrict__ Zxc, const u16* __restrict__ WT,
    const float* __restrict__ inputo, const float* __restrict__ bias,
    const float* __restrict__ ln_w, const float* __restrict__ ln_b,
    float* __restrict__ out, u16* __restrict__ hx, float* __restrict__ cxbuf,
    float* __restrict__ gpart, unsigned* __restrict__ flags,
    int t0, int log2Tc) {
  __shared__ __align__(16) u16 hxS[32 * 1024]; // [row][k8' ^ (row&7) swizzled], 64KB
  __shared__ __align__(16) u16 zxS[32 * 64];   // [row][c8' ^ (row&7) swizzled], 4KB
  __shared__ __align__(16) float zbuf[32][68];
  __shared__ float spart[4][32][2];
  __shared__ float stot[32][2];

  const int Tc = 1 << log2Tc;
  const int tid = threadIdx.x, lane = tid & 63, wv = tid >> 6;
  const int rg = blockIdx.x >> 6, wslice = blockIdx.x & 63;
  const int f0 = wslice << 4;
  const int l15 = lane & 15, kg = lane >> 4;
  const int n = (wv << 10) + f0 + l15;     // this lane's output col (gate=wv)
  const float lnw = ln_w[n], lnb = ln_b[n], bz = bias[n];
  unsigned* mycnt = flags + (((rg << 3) + (wslice & 7)) << 5);

  // ---- B preload into VGPRs: Wh[k][n] = WT[n][2048+k], 32 k-blocks
  s16x8 bfrag[32];
  {
    const u16* bp = WT + (size_t)n * 3072 + 2048 + (kg << 3);
#pragma unroll
    for (int kb = 0; kb < 32; ++kb) bfrag[kb] = *(const s16x8*)(bp + (kb << 5));
  }

  // phase-B role: thread -> (row, feature pair)
  const int prow = tid >> 3;
  const int pf = (tid & 7) << 1;
  const int pr = (rg << 5) + prow;
  const int pfg = f0 + pf;
  float2 cx = *(const float2*)(cxbuf + pr * 1024 + pfg);

  const int arow0 = l15, arow1 = 16 + l15;
  unsigned ev = 2u * (unsigned)t0; // events completed so far (global, monotone)

  for (int tc = 0; tc < Tc; ++tc) {
    const int t = t0 + tc;
    // ---- stage hx -> hxS via global_load_lds; source pre-swizzled so
    // ds_read_b128 A-frags (row stride 2KB) are conflict-free.
#pragma unroll
    for (int it = 0; it < 16; ++it) {
      int chunk = (wv << 4) + it;
      int row = chunk >> 1;
      int k8p = ((chunk & 1) << 6) | lane;
      gload_lds16(hx + (((rg << 5) + row) << 10) + ((k8p ^ (row & 7)) << 3),
                  (char*)hxS + (chunk << 10));
    }
    // ---- stage Zx slice (32 rows x 64 cols bf16, one issue), source pre-swizzled
    {
      int sl = (wv << 6) + lane;
      int row = sl >> 3, c8p = sl & 7;
      int c8 = c8p ^ (row & 7);
      size_t m = ((size_t)((rg << 5) + row) << log2Tc) + tc;
      gload_lds16(Zxc + m * 4096 + ((size_t)(c8 >> 1) << 10) + f0 + ((c8 & 1) << 3),
                  (char*)zxS + (wv << 10));
    }
    float2 inv = *(const float2*)(inputo + ((size_t)pr * 256 + t) * 1024 + pfg);
    __syncthreads(); // drains gload_lds + visibility

    // ---- GEMM: z[32 rows][16 cols] per wave, K=1024, B from VGPRs
    f32x4 acc0 = (f32x4){0.f, 0.f, 0.f, 0.f};
    f32x4 acc1 = (f32x4){0.f, 0.f, 0.f, 0.f};
#pragma unroll
    for (int kb = 0; kb < 32; ++kb) {
      int k8 = (kb << 2) | kg;
      s16x8 a0 = *(const s16x8*)(hxS + (arow0 << 10) + ((k8 ^ (arow0 & 7)) << 3));
      s16x8 a1 = *(const s16x8*)(hxS + (arow1 << 10) + ((k8 ^ (arow1 & 7)) << 3));
      acc0 = mfma16(a0, bfrag[kb], acc0);
      acc1 = mfma16(a1, bfrag[kb], acc1);
    }

    // ---- z = acc + zx + bias, partial stats over this wave's 16 cols
    float z[2][4], s1[2][4], s2[2][4];
    const int c8base = (wv << 1) + (l15 >> 3);
#pragma unroll
    for (int rt = 0; rt < 2; ++rt) {
#pragma unroll
      for (int j = 0; j < 4; ++j) {
        int row = rt * 16 + (kg << 2) + j;
        float zx = bf2f(zxS[(row << 6) + ((c8base ^ (row & 7)) << 3) + (l15 & 7)]);
        float zv = (rt ? acc1[j] : acc0[j]) + zx + bz;
        z[rt][j] = zv;
        s1[rt][j] = zv;
        s2[rt][j] = zv * zv;
      }
    }
#pragma unroll
    for (int off = 1; off < 16; off <<= 1) {
#pragma unroll
      for (int rt = 0; rt < 2; ++rt)
#pragma unroll
        for (int j = 0; j < 4; ++j) {
          s1[rt][j] += __shfl_xor(s1[rt][j], off, 64);
          s2[rt][j] += __shfl_xor(s2[rt][j], off, 64);
        }
    }
    if (l15 == 0) {
#pragma unroll
      for (int rt = 0; rt < 2; ++rt)
#pragma unroll
        for (int j = 0; j < 4; ++j) {
          int row = rt * 16 + (kg << 2) + j;
          spart[wv][row][0] = s1[rt][j];
          spart[wv][row][1] = s2[rt][j];
        }
    }
    __syncthreads();
    if (tid < 64) {
      int row = tid >> 1, kind = tid & 1;
      float s = spart[0][row][kind] + spart[1][row][kind] +
                spart[2][row][kind] + spart[3][row][kind];
      gpart[(((rg << 6) + (row << 1) + kind) << 6) + wslice] = s;
    }
    mbar(flags, mycnt, rg, 8u * (ev + 1), false); ++ev; // stats partials visible

    // ---- reduce stats across 64 slices, LN, gates, state update
    if (tid < 64) {
      int row = tid >> 1, kind = tid & 1;
      const float4* p = (const float4*)(gpart + ((size_t)(((rg << 6) + (row << 1) + kind)) << 6));
      float s = 0.f;
#pragma unroll 4
      for (int q = 0; q < 16; ++q) { float4 v = p[q]; s += (v.x + v.y) + (v.z + v.w); }
      stot[row][kind] = s;
    }
    __syncthreads();
#pragma unroll
    for (int rt = 0; rt < 2; ++rt) {
#pragma unroll
      for (int j = 0; j < 4; ++j) {
        int row = rt * 16 + (kg << 2) + j;
        float mean = stot[row][0] * (1.f / 4096.f);
        float var = stot[row][1] * (1.f / 4096.f) - mean * mean;
        float rstd = 1.f / sqrtf(var + LN_EPS);
        zbuf[row][(wv << 4) + l15] = (z[rt][j] - mean) * rstd * lnw + lnb;
      }
    }
    __syncthreads();
    {
      float2 zi = *(const float2*)&zbuf[prow][pf];
      float2 zf = *(const float2*)&zbuf[prow][16 + pf];
      float2 zo = *(const float2*)&zbuf[prow][32 + pf];
      float2 zh = *(const float2*)&zbuf[prow][48 + pf];
      float ig0 = 1.f / (1.f + expf(-zi.x)), ig1 = 1.f / (1.f + expf(-zi.y));
      float fg0 = 1.f / (1.f + expf(-zf.x)), fg1 = 1.f / (1.f + expf(-zf.y));
      float og0 = 1.f / (1.f + expf(-zo.x)), og1 = 1.f / (1.f + expf(-zo.y));
      float h0 = 0.5f * zh.x * (1.f + erff(zh.x * 0.70710678118654752f));
      float h1 = 0.5f * zh.y * (1.f + erff(zh.y * 0.70710678118654752f));
      cx.x = fg0 * cx.x + ig0 * h0;
      cx.y = fg1 * cx.y + ig1 * h1;
      float hx0 = og0 * cx.x, hx1 = og1 * cx.y;
      float2 ov = { hx0 + inv.x, hx1 + inv.y };
      *(float2*)(out + ((size_t)pr * 256 + t) * 1024 + pfg) = ov;
      u32 hpack = (u32)f2bf(hx0) | ((u32)f2bf(hx1) << 16);
      *(u32*)(hx + pr * 1024 + pfg) = hpack;
    }
    mbar(flags, mycnt, rg, 8u * (ev + 1), tc == Tc - 1); ++ev; // hx(t) visible
  }
  *(float2*)(cxbuf + pr * 1024 + pfg) = cx;
}

// ---------- launch ----------
extern "C" void kernel_launch(void* const* d_in, const int* in_sizes, int n_in,
                              void* d_out, int out_size, void* d_ws, size_t ws_size,
                              hipStream_t stream) {
  const float* inputo  = (const float*)d_in[0];
  const float* attn    = (const float*)d_in[1];
  const float* W       = (const float*)d_in[2];
  const float* bias    = (const float*)d_in[3];
  const float* ln_w    = (const float*)d_in[4];
  const float* ln_b    = (const float*)d_in[5];
  const float* init_hx = (const float*)d_in[6];
  const float* init_cx = (const float*)d_in[7];
  float* out = (float*)d_out;

  const size_t WT_BYTES = (size_t)4096 * 3072 * 2;            // 24 MiB
  const size_t TAIL     = 131072 + 262144 + 32768 + 2048;     // hx, cx, gpart, flags
  int log2Tc = 7;
  for (; log2Tc > 2; --log2Tc) {
    size_t Tc = (size_t)1 << log2Tc;
    size_t need = WT_BYTES + Tc * 262144 /*Xc*/ + Tc * 524288 /*Zxc*/ + TAIL;
    if (need <= ws_size) break;
  }
  const int Tc = 1 << log2Tc;
  const int nchunks = 256 / Tc;

  char* ws = (char*)d_ws;
  size_t off = 0;
  u16* WT       = (u16*)(ws + off); off += WT_BYTES;
  u16* Xc       = (u16*)(ws + off); off += (size_t)Tc * 262144;
  u16* Zxc      = (u16*)(ws + off); off += (size_t)Tc * 524288;
  u16* hx       = (u16*)(ws + off); off += 131072;
  float* cxbuf  = (float*)(ws + off); off += 262144;
  float* gpart  = (float*)(ws + off); off += 32768;
  unsigned* flg = (unsigned*)(ws + off);

  wtrans_kernel<<<12288, 256, 0, stream>>>(W, WT);
  init_kernel<<<256, 256, 0, stream>>>(init_hx, init_cx, hx, cxbuf, flg);

  for (int c = 0; c < nchunks; ++c) {
    int t0 = c * Tc;
    cvtx_kernel<<<64 * Tc, 256, 0, stream>>>(inputo, attn, Xc, t0, log2Tc);
    gemm_zx_kernel<<<(Tc / 2) * 32, 256, 0, stream>>>(Xc, WT, Zxc, log2Tc - 1);
    recurrent_kernel<<<128, 256, 0, stream>>>(Zxc, WT, inputo, bias, ln_w, ln_b,
                                              out, hx, cxbuf, gpart, flg, t0, log2Tc);
  }
}

// Round 4
// 4885.313 us; speedup vs baseline: 4.7767x; 1.1765x over previous
//
#include <hip/hip_runtime.h>
#include <cmath>

typedef unsigned short u16;
typedef unsigned int u32;
typedef unsigned long long u64;
typedef __attribute__((ext_vector_type(8))) short s16x8;
typedef __attribute__((ext_vector_type(8))) unsigned short u16x8;
typedef __attribute__((ext_vector_type(4))) unsigned short u16x4;
typedef __attribute__((ext_vector_type(4))) float f32x4;

#define LN_EPS 1e-6f
#define SCOPE_AGENT __HIP_MEMORY_SCOPE_AGENT

// ---------- helpers ----------
__device__ __forceinline__ u16 f2bf(float f) {
  union { float f; u32 u; } v; v.f = f;
  u32 r = v.u + 0x7FFFu + ((v.u >> 16) & 1u);
  return (u16)(r >> 16);
}
__device__ __forceinline__ float bf2f(u16 h) {
  union { u32 u; float f; } v; v.u = ((u32)h) << 16; return v.f;
}

// coherent (cache-bypassing, fence-free) accessors for cross-wg data
__device__ __forceinline__ u32 aload32(const u32* p) {
  return __hip_atomic_load(p, __ATOMIC_RELAXED, SCOPE_AGENT);
}
__device__ __forceinline__ void astore32(u32* p, u32 v) {
  __hip_atomic_store(p, v, __ATOMIC_RELAXED, SCOPE_AGENT);
}
__device__ __forceinline__ u64 aload64(const u64* p) {
  return __hip_atomic_load(p, __ATOMIC_RELAXED, SCOPE_AGENT);
}

__device__ __forceinline__ void gload_lds16(const void* g, void* l) {
  __builtin_amdgcn_global_load_lds(
      (__attribute__((address_space(1))) void*)g,
      (__attribute__((address_space(3))) void*)l, 16, 0, 0);
}

__device__ __forceinline__ f32x4 mfma16(s16x8 a, s16x8 b, f32x4 c) {
  return __builtin_amdgcn_mfma_f32_16x16x32_bf16(a, b, c, 0, 0, 0);
}

// machine barrier, fence-free: per-wg flag WORD (store, no RMW), relaxed poll.
// Data communicated across wgs travels via aload/astore (sc-coherent), so no
// L2 writeback/invalidate is ever needed.
__device__ __forceinline__ void mbar(u32* flags, int rg, int wslice,
                                     unsigned tgt, bool skip_poll) {
  __syncthreads(); // each wave drains its vmcnt before s_barrier -> stores done
  if (threadIdx.x == 0) astore32(&flags[(rg << 7) + wslice], tgt);
  if (!skip_poll) {
    if (threadIdx.x < 64) {
      unsigned v;
      do {
        v = aload32(&flags[(rg << 7) + threadIdx.x]);
      } while (__all(v >= tgt) == 0);
    }
    __syncthreads();
  }
}

// ---------- kernel 1: Xc[m][2048] = bf16(concat(inputo, attn)), m=b*Tc+tc ----------
__global__ __launch_bounds__(256) void cvtx_kernel(const float* __restrict__ inputo,
                                                   const float* __restrict__ attn,
                                                   u16* __restrict__ Xc,
                                                   int t0, int log2Tc) {
  size_t i = ((size_t)blockIdx.x * 256 + threadIdx.x) * 4;
  size_t m = i >> 10, d = i & 1023;
  int tc = (int)(m & ((1u << log2Tc) - 1));
  int b  = (int)(m >> log2Tc);
  size_t src = ((size_t)b * 256 + t0 + tc) * 1024 + d;
  float4 a = *(const float4*)(inputo + src);
  float4 v = *(const float4*)(attn + src);
  u16x4 va = { f2bf(a.x), f2bf(a.y), f2bf(a.z), f2bf(a.w) };
  u16x4 vb = { f2bf(v.x), f2bf(v.y), f2bf(v.z), f2bf(v.w) };
  *(u16x4*)(Xc + m * 2048 + d) = va;
  *(u16x4*)(Xc + m * 2048 + 1024 + d) = vb;
}

// ---------- kernel 2: WT[n][k] = bf16(W[k][n]) ----------
__global__ __launch_bounds__(256) void wtrans_kernel(const float* __restrict__ W,
                                                     u16* __restrict__ WT) {
  __shared__ float tile[32][33];
  int bn = blockIdx.x & 127;
  int bk = blockIdx.x >> 7;
  int n0 = bn * 32, k0 = bk * 32;
  int tx = threadIdx.x & 31, ty = threadIdx.x >> 5;
#pragma unroll
  for (int i = 0; i < 32; i += 8)
    tile[ty + i][tx] = W[(size_t)(k0 + ty + i) * 4096 + n0 + tx];
  __syncthreads();
#pragma unroll
  for (int i = 0; i < 32; i += 8)
    WT[(size_t)(n0 + ty + i) * 3072 + k0 + tx] = f2bf(tile[tx][ty + i]);
}

// ---------- kernel 3: init hx, cx, flags ----------
__global__ __launch_bounds__(256) void init_kernel(const float* __restrict__ init_hx,
                                                   const float* __restrict__ init_cx,
                                                   u16* __restrict__ hx,
                                                   float* __restrict__ cxbuf,
                                                   u32* __restrict__ flags) {
  int i = blockIdx.x * 256 + threadIdx.x;
  if (i < 64 * 1024) {
    hx[i] = f2bf(init_hx[i & 1023]);
    cxbuf[i] = init_cx[i & 1023];
  }
  if (i < 512) flags[i] = 0;
}

// ---------- kernel 4: Zxc[m][n] = bf16( sum_k Xc[m][k]*WT[n][k] ) ----------
__global__ __launch_bounds__(256) void gemm_zx_kernel(const u16* __restrict__ Xc,
                                                      const u16* __restrict__ WT,
                                                      u16* __restrict__ Zxc,
                                                      int log2nmt) {
  __shared__ u16 As[128 * 64];
  __shared__ u16 Bs[128 * 64];
  const int tid = threadIdx.x, lane = tid & 63, wave = tid >> 6;
  const int nmt_mask = (1 << log2nmt) - 1;
  int mt = blockIdx.x & nmt_mask;
  int nt = blockIdx.x >> log2nmt;
  const size_t m0 = (size_t)mt * 128, n0 = (size_t)nt * 128;
  const int wm = (wave >> 1) * 64, wn = (wave & 1) * 64;
  const int l15 = lane & 15, kg = lane >> 4;
  const int s_r = lane >> 3;
  const int s_c = (lane & 7) * 8;

  f32x4 acc[4][4];
#pragma unroll
  for (int a = 0; a < 4; ++a)
#pragma unroll
    for (int b = 0; b < 4; ++b) acc[a][b] = (f32x4){0.f, 0.f, 0.f, 0.f};

  for (int k0 = 0; k0 < 2048; k0 += 64) {
#pragma unroll
    for (int it = 0; it < 4; ++it) {
      int ch = (wave << 2) + it;
      int row = (ch << 3) + s_r;
      gload_lds16(Xc + (m0 + row) * 2048 + k0 + s_c, (char*)As + (ch << 10));
      gload_lds16(WT + (n0 + row) * 3072 + k0 + s_c, (char*)Bs + (ch << 10));
    }
    __syncthreads();
#pragma unroll
    for (int kk = 0; kk < 2; ++kk) {
      s16x8 af[4], bf[4];
#pragma unroll
      for (int i = 0; i < 4; ++i)
        af[i] = *(const s16x8*)(As + (wm + i * 16 + l15) * 64 + kk * 32 + kg * 8);
#pragma unroll
      for (int i = 0; i < 4; ++i)
        bf[i] = *(const s16x8*)(Bs + (wn + i * 16 + l15) * 64 + kk * 32 + kg * 8);
#pragma unroll
      for (int mi = 0; mi < 4; ++mi)
#pragma unroll
        for (int ni = 0; ni < 4; ++ni)
          acc[mi][ni] = mfma16(af[mi], bf[ni], acc[mi][ni]);
    }
    __syncthreads();
  }
#pragma unroll
  for (int ni = 0; ni < 4; ++ni) {
    size_t n = n0 + wn + ni * 16 + l15;
#pragma unroll
    for (int mi = 0; mi < 4; ++mi) {
#pragma unroll
      for (int j = 0; j < 4; ++j) {
        size_t m = m0 + wm + mi * 16 + (kg << 2) + j;
        Zxc[m * 4096 + n] = f2bf(acc[mi][ni][j]);
      }
    }
  }
}

// ---------- kernel 5: persistent recurrence, 2 machines x 64 wgs x 256 thr ----------
// machine rg: rows rg*32..+32, all 4096 cols. wg wslice: 16 features x 4 gates.
// Cross-wg data (hx, gpart, flags) via relaxed agent atomics (sc-coherent,
// fence-free). Private data (Zxc, inputo, out) on the normal cached path.
__global__ __launch_bounds__(256, 1) void recurrent_kernel(
    const u16* __restrict__ Zxc, const u16* __restrict__ WT,
    const float* __restrict__ inputo, const float* __restrict__ bias,
    const float* __restrict__ ln_w, const float* __restrict__ ln_b,
    float* __restrict__ out, u16* __restrict__ hx, float* __restrict__ cxbuf,
    u32* __restrict__ gpart, u32* __restrict__ flags,
    int t0, int log2Tc) {
  __shared__ __align__(16) u16 hxS[32 * 1024]; // [row][16B slot k8p = k8^(row&7)], 64KB
  __shared__ __align__(16) u16 zxS[32 * 64];   // [row][c8' ^ (row&7) swizzled], 4KB
  __shared__ __align__(16) float zbuf[32][68];
  __shared__ float spart[4][32][2];
  __shared__ float stot[32][2];

  const int Tc = 1 << log2Tc;
  const int tid = threadIdx.x, lane = tid & 63, wv = tid >> 6;
  const int rg = blockIdx.x >> 6, wslice = blockIdx.x & 63;
  const int f0 = wslice << 4;
  const int l15 = lane & 15, kg = lane >> 4;
  const int n = (wv << 10) + f0 + l15;     // this lane's output col (gate=wv)
  const float lnw = ln_w[n], lnb = ln_b[n], bz = bias[n];

  // ---- B preload into VGPRs: Wh[k][n] = WT[n][2048+k], 32 k-blocks
  s16x8 bfrag[32];
  {
    const u16* bp = WT + (size_t)n * 3072 + 2048 + (kg << 3);
#pragma unroll
    for (int kb = 0; kb < 32; ++kb) bfrag[kb] = *(const s16x8*)(bp + (kb << 5));
  }

  // phase-B role: thread -> (row, feature pair)
  const int prow = tid >> 3;
  const int pf = (tid & 7) << 1;
  const int pr = (rg << 5) + prow;
  const int pfg = f0 + pf;
  float2 cx = *(const float2*)(cxbuf + pr * 1024 + pfg);

  const int arow0 = l15, arow1 = 16 + l15;
  const u64* hxM = (const u64*)(hx + ((size_t)rg << 15)); // machine's 32x1024 block
  unsigned ev = 2u * (unsigned)t0; // monotone event counter

  for (int tc = 0; tc < Tc; ++tc) {
    const int t = t0 + tc;
    // ---- stage hx -> hxS via coherent 8B loads + ds_write_b64.
    // u64 slot s (0..8191): chunk c=s>>1, half h=s&1; row=c>>7, k8p=c&127,
    // source k8 = k8p^(row&7)  => GEMM A-frag reads (slot k8^(arow&7)) are
    // conflict-free (row stride 2KB) exactly as before.
#pragma unroll 8
    for (int it = 0; it < 32; ++it) {
      int s = (it << 8) + tid;
      int c = s >> 1, h = s & 1;
      int row = c >> 7, k8p = c & 127;
      int k8 = k8p ^ (row & 7);
      u64 v = aload64(hxM + ((row << 7) + k8) * 2 + h);
      ((u64*)hxS)[s] = v;
    }
    // ---- stage Zx slice (32 rows x 64 cols bf16, one issue), source pre-swizzled
    {
      int sl = (wv << 6) + lane;
      int row = sl >> 3, c8p = sl & 7;
      int c8 = c8p ^ (row & 7);
      size_t m = ((size_t)((rg << 5) + row) << log2Tc) + tc;
      gload_lds16(Zxc + m * 4096 + ((size_t)(c8 >> 1) << 10) + f0 + ((c8 & 1) << 3),
                  (char*)zxS + (wv << 10));
    }
    float2 inv = *(const float2*)(inputo + ((size_t)pr * 256 + t) * 1024 + pfg);
    __syncthreads(); // drains loads + LDS visibility

    // ---- GEMM: z[32 rows][16 cols] per wave, K=1024, B from VGPRs
    f32x4 acc0 = (f32x4){0.f, 0.f, 0.f, 0.f};
    f32x4 acc1 = (f32x4){0.f, 0.f, 0.f, 0.f};
#pragma unroll
    for (int kb = 0; kb < 32; ++kb) {
      int k8 = (kb << 2) | kg;
      s16x8 a0 = *(const s16x8*)(hxS + (arow0 << 10) + ((k8 ^ (arow0 & 7)) << 3));
      s16x8 a1 = *(const s16x8*)(hxS + (arow1 << 10) + ((k8 ^ (arow1 & 7)) << 3));
      acc0 = mfma16(a0, bfrag[kb], acc0);
      acc1 = mfma16(a1, bfrag[kb], acc1);
    }

    // ---- z = acc + zx + bias, partial stats over this wave's 16 cols
    float z[2][4], s1[2][4], s2[2][4];
    const int c8base = (wv << 1) + (l15 >> 3);
#pragma unroll
    for (int rt = 0; rt < 2; ++rt) {
#pragma unroll
      for (int j = 0; j < 4; ++j) {
        int row = rt * 16 + (kg << 2) + j;
        float zx = bf2f(zxS[(row << 6) + ((c8base ^ (row & 7)) << 3) + (l15 & 7)]);
        float zv = (rt ? acc1[j] : acc0[j]) + zx + bz;
        z[rt][j] = zv;
        s1[rt][j] = zv;
        s2[rt][j] = zv * zv;
      }
    }
#pragma unroll
    for (int off = 1; off < 16; off <<= 1) {
#pragma unroll
      for (int rt = 0; rt < 2; ++rt)
#pragma unroll
        for (int j = 0; j < 4; ++j) {
          s1[rt][j] += __shfl_xor(s1[rt][j], off, 64);
          s2[rt][j] += __shfl_xor(s2[rt][j], off, 64);
        }
    }
    if (l15 == 0) {
#pragma unroll
      for (int rt = 0; rt < 2; ++rt)
#pragma unroll
        for (int j = 0; j < 4; ++j) {
          int row = rt * 16 + (kg << 2) + j;
          spart[wv][row][0] = s1[rt][j];
          spart[wv][row][1] = s2[rt][j];
        }
    }
    __syncthreads();
    if (tid < 64) { // tid = (row<<1)|kind ; producer-coalesced gpart write
      int row = tid >> 1, kind = tid & 1;
      float s = spart[0][row][kind] + spart[1][row][kind] +
                spart[2][row][kind] + spart[3][row][kind];
      astore32(&gpart[(rg << 12) + (wslice << 6) + tid], __float_as_uint(s));
    }
    mbar(flags, rg, wslice, ++ev, false); // stats partials visible

    // ---- reduce stats across 64 slices (coalesced across lanes), LN, gates
    if (tid < 64) {
      float s = 0.f;
#pragma unroll 8
      for (int q = 0; q < 64; ++q)
        s += __uint_as_float(aload32(&gpart[(rg << 12) + (q << 6) + tid]));
      stot[tid >> 1][tid & 1] = s;
    }
    __syncthreads();
#pragma unroll
    for (int rt = 0; rt < 2; ++rt) {
#pragma unroll
      for (int j = 0; j < 4; ++j) {
        int row = rt * 16 + (kg << 2) + j;
        float mean = stot[row][0] * (1.f / 4096.f);
        float var = stot[row][1] * (1.f / 4096.f) - mean * mean;
        float rstd = 1.f / sqrtf(var + LN_EPS);
        zbuf[row][(wv << 4) + l15] = (z[rt][j] - mean) * rstd * lnw + lnb;
      }
    }
    __syncthreads();
    {
      float2 zi = *(const float2*)&zbuf[prow][pf];
      float2 zf = *(const float2*)&zbuf[prow][16 + pf];
      float2 zo = *(const float2*)&zbuf[prow][32 + pf];
      float2 zh = *(const float2*)&zbuf[prow][48 + pf];
      float ig0 = 1.f / (1.f + expf(-zi.x)), ig1 = 1.f / (1.f + expf(-zi.y));
      float fg0 = 1.f / (1.f + expf(-zf.x)), fg1 = 1.f / (1.f + expf(-zf.y));
      float og0 = 1.f / (1.f + expf(-zo.x)), og1 = 1.f / (1.f + expf(-zo.y));
      float h0 = 0.5f * zh.x * (1.f + erff(zh.x * 0.70710678118654752f));
      float h1 = 0.5f * zh.y * (1.f + erff(zh.y * 0.70710678118654752f));
      cx.x = fg0 * cx.x + ig0 * h0;
      cx.y = fg1 * cx.y + ig1 * h1;
      float hx0 = og0 * cx.x, hx1 = og1 * cx.y;
      float2 ov = { hx0 + inv.x, hx1 + inv.y };
      *(float2*)(out + ((size_t)pr * 256 + t) * 1024 + pfg) = ov;
      u32 hpack = (u32)f2bf(hx0) | ((u32)f2bf(hx1) << 16);
      astore32((u32*)(hx + pr * 1024 + pfg), hpack);
    }
    mbar(flags, rg, wslice, ++ev, tc == Tc - 1); // hx(t) visible
  }
  *(float2*)(cxbuf + pr * 1024 + pfg) = cx;
}

// ---------- launch ----------
extern "C" void kernel_launch(void* const* d_in, const int* in_sizes, int n_in,
                              void* d_out, int out_size, void* d_ws, size_t ws_size,
                              hipStream_t stream) {
  const float* inputo  = (const float*)d_in[0];
  const float* attn    = (const float*)d_in[1];
  const float* W       = (const float*)d_in[2];
  const float* bias    = (const float*)d_in[3];
  const float* ln_w    = (const float*)d_in[4];
  const float* ln_b    = (const float*)d_in[5];
  const float* init_hx = (const float*)d_in[6];
  const float* init_cx = (const float*)d_in[7];
  float* out = (float*)d_out;

  const size_t WT_BYTES = (size_t)4096 * 3072 * 2;            // 24 MiB
  const size_t TAIL     = 131072 + 262144 + 32768 + 2048;     // hx, cx, gpart, flags
  int log2Tc = 7;
  for (; log2Tc > 2; --log2Tc) {
    size_t Tc = (size_t)1 << log2Tc;
    size_t need = WT_BYTES + Tc * 262144 /*Xc*/ + Tc * 524288 /*Zxc*/ + TAIL;
    if (need <= ws_size) break;
  }
  const int Tc = 1 << log2Tc;
  const int nchunks = 256 / Tc;

  char* ws = (char*)d_ws;
  size_t off = 0;
  u16* WT       = (u16*)(ws + off); off += WT_BYTES;
  u16* Xc       = (u16*)(ws + off); off += (size_t)Tc * 262144;
  u16* Zxc      = (u16*)(ws + off); off += (size_t)Tc * 524288;
  u16* hx       = (u16*)(ws + off); off += 131072;
  float* cxbuf  = (float*)(ws + off); off += 262144;
  u32* gpart    = (u32*)(ws + off); off += 32768;
  u32* flg      = (u32*)(ws + off);

  wtrans_kernel<<<12288, 256, 0, stream>>>(W, WT);
  init_kernel<<<256, 256, 0, stream>>>(init_hx, init_cx, hx, (float*)cxbuf, flg);

  for (int c = 0; c < nchunks; ++c) {
    int t0 = c * Tc;
    cvtx_kernel<<<64 * Tc, 256, 0, stream>>>(inputo, attn, Xc, t0, log2Tc);
    gemm_zx_kernel<<<(Tc / 2) * 32, 256, 0, stream>>>(Xc, WT, Zxc, log2Tc - 1);
    recurrent_kernel<<<128, 256, 0, stream>>>(Zxc, WT, inputo, bias, ln_w, ln_b,
                                              out, hx, cxbuf, gpart, flg, t0, log2Tc);
  }
}